// Round 5
// baseline (23948.715 us; speedup 1.0000x reference)
//
#include <hip/hip_runtime.h>
#include <stdint.h>

// ---------------------------------------------------------------------------
// AVAttention — ROUND 5: round-4 naive pipeline, single change: d_out is
// FLOAT32 (reference's output dtype per harness contract), not bf16.
// B=16, S=1024, T=2048, D=512, CF=2560, MEL=1280. Inputs fp32 (sniffed, bf16
// hedge); intermediates bf16; output fp32 [B,64,20,T].
// d_out (168MB fp32) hosts scratch in its first 84MB: sc [B][T][S] bf16 +
// kT [B][D][S] bf16; final GEMM overwrites all of d_out with fp32.
// ---------------------------------------------------------------------------

__device__ __forceinline__ ushort f2b(float x) {
    union { float f; uint32_t u; } v; v.f = x;
    uint32_t r = (v.u + 0x7FFFu + ((v.u >> 16) & 1u)) >> 16;
    return (ushort)r;
}
__device__ __forceinline__ float b2f(ushort u) {
    union { uint32_t u; float f; } v; v.u = ((uint32_t)u) << 16;
    return v.f;
}

// flag: 1 = inputs bf16, 0 = fp32. For bf16 data the LOW half of each 32-bit
// word is a plausible bf16 (exp in [90,140] for N(0,1)) -> cnt~64; for fp32
// the low half is random mantissa bits -> cnt~13.
__global__ void sniff_dtype(const uint32_t* __restrict__ ph, int* __restrict__ flag)
{
    if (threadIdx.x == 0 && blockIdx.x == 0) {
        int cnt = 0;
        for (int i = 0; i < 64; ++i) {
            uint32_t e = (ph[i] >> 7) & 0xFFu;
            if (e >= 90u && e <= 140u) ++cnt;
        }
        *flag = (cnt >= 40) ? 1 : 0;
    }
}

// Naive GEMM: C[m][n] = scale * sum_k A[ars*m + acs*k] * B[bks*k + bns*n]
//             (+ bias[n]). One thread per output. Block (16,16).
// ARAW/BRAW: operand uses flag-dtype (fp32/bf16); else bf16.
// STORE: 0 plain bf16 C[m*ldc+n]; 1 transposed bf16 C[n*ldc+m];
//        2 FINAL FP32 out C[(n&63)*(20*2048) + (n>>6)*2048 + m].
// HASBIAS: bias[n] in raw input dtype.
template<int ARAW, int BRAW, int STORE, int HASBIAS>
__global__ __launch_bounds__(256)
void ngemm(const void* __restrict__ A, const void* __restrict__ B,
           void* __restrict__ C, const void* __restrict__ bias,
           int M, int N, int K,
           long ars, long acs, long abat,
           long bks, long bns, long bbat,
           long ldc, long cbat, float scale,
           const int* __restrict__ flag)
{
    const bool isf32 = (*flag == 0);
    const int n = blockIdx.x * 16 + threadIdx.x;
    const int m = blockIdx.y * 16 + threadIdx.y;
    if (m >= M || n >= N) return;

    const char* Ab = (const char*)A + (size_t)blockIdx.z * abat * ((ARAW && isf32) ? 4 : 2);
    const char* Bb = (const char*)B + (size_t)blockIdx.z * bbat * ((BRAW && isf32) ? 4 : 2);

    float acc = 0.f;
    if ((ARAW && isf32) || (BRAW && isf32)) {
        if (ARAW && BRAW) {
            const float* Af = (const float*)Ab;
            const float* Bf = (const float*)Bb;
#pragma unroll 8
            for (int k = 0; k < K; ++k)
                acc += Af[ars * m + acs * k] * Bf[bks * k + bns * n];
        } else if (ARAW) {
            const float* Af = (const float*)Ab;
            const ushort* Bh = (const ushort*)Bb;
#pragma unroll 8
            for (int k = 0; k < K; ++k)
                acc += Af[ars * m + acs * k] * b2f(Bh[bks * k + bns * n]);
        } else {
            const ushort* Ah = (const ushort*)Ab;
            const float* Bf = (const float*)Bb;
#pragma unroll 8
            for (int k = 0; k < K; ++k)
                acc += b2f(Ah[ars * m + acs * k]) * Bf[bks * k + bns * n];
        }
    } else {
        const ushort* Ah = (const ushort*)Ab;
        const ushort* Bh = (const ushort*)Bb;
#pragma unroll 8
        for (int k = 0; k < K; ++k)
            acc += b2f(Ah[ars * m + acs * k]) * b2f(Bh[bks * k + bns * n]);
    }

    acc *= scale;
    if (HASBIAS)
        acc += isf32 ? ((const float*)bias)[n] : b2f(((const ushort*)bias)[n]);

    if (STORE == 0) {
        ushort* Cb = (ushort*)C + (size_t)blockIdx.z * cbat;
        Cb[(size_t)m * ldc + n] = f2b(acc);
    } else if (STORE == 1) {
        ushort* Cb = (ushort*)C + (size_t)blockIdx.z * cbat;
        Cb[(size_t)n * ldc + m] = f2b(acc);
    } else {
        float* Cb = (float*)C + (size_t)blockIdx.z * cbat;   // FP32 final output
        Cb[(size_t)(n & 63) * (20 * 2048)
           + (size_t)(n >> 6) * 2048 + (size_t)m] = acc;
    }
}

// In-place masked softmax over rows of sc[B][T][S], S=1024, block=256.
__global__ __launch_bounds__(256)
void softmax_mask(ushort* __restrict__ sc, const int* __restrict__ lengths)
{
    const int t = blockIdx.x, b = blockIdx.y, tid = threadIdx.x;
    // int64 positive values => odd 32-bit words are 0; int32 lengths >= 1
    // => cannot false-positive.
    const bool is64 = (lengths[1] == 0 && lengths[3] == 0 && lengths[5] == 0);
    const int len = is64 ? lengths[2 * b] : lengths[b];

    ushort* row = sc + ((size_t)b * 2048 + t) * 1024;
    const int s0 = tid * 4;
    uint2 pk = *(const uint2*)(row + s0);
    ushort u[4] = { (ushort)(pk.x & 0xffff), (ushort)(pk.x >> 16),
                    (ushort)(pk.y & 0xffff), (ushort)(pk.y >> 16) };
    float v[4];
    float mx = -INFINITY;
#pragma unroll
    for (int j = 0; j < 4; ++j) {
        v[j] = (s0 + j < len) ? b2f(u[j]) : -INFINITY;
        mx = fmaxf(mx, v[j]);
    }
    for (int off = 32; off > 0; off >>= 1) mx = fmaxf(mx, __shfl_xor(mx, off));
    __shared__ float redm[4], reds[4];
    const int w = tid >> 6;
    if ((tid & 63) == 0) redm[w] = mx;
    __syncthreads();
    mx = fmaxf(fmaxf(redm[0], redm[1]), fmaxf(redm[2], redm[3]));

    float e[4]; float sum = 0.f;
#pragma unroll
    for (int j = 0; j < 4; ++j) { e[j] = __expf(v[j] - mx); sum += e[j]; }
    for (int off = 32; off > 0; off >>= 1) sum += __shfl_xor(sum, off);
    if ((tid & 63) == 0) reds[w] = sum;
    __syncthreads();
    sum = reds[0] + reds[1] + reds[2] + reds[3];
    const float inv = 1.0f / sum;

    ushort o[4];
#pragma unroll
    for (int j = 0; j < 4; ++j) o[j] = f2b(e[j] * inv);
    uint2 opk;
    opk.x = (uint32_t)o[0] | ((uint32_t)o[1] << 16);
    opk.y = (uint32_t)o[2] | ((uint32_t)o[3] << 16);
    *(uint2*)(row + s0) = opk;
}

extern "C" void kernel_launch(void* const* d_in, const int* in_sizes, int n_in,
                              void* d_out, int out_size, void* d_ws, size_t ws_size,
                              hipStream_t stream)
{
    const void* ph   = d_in[0];   // [16,1024,512]
    const void* g    = d_in[1];   // [16,2560,2048]
    const int*  len  = (const int*)d_in[2];
    const void* Wk   = d_in[3];   // [512,512]  (W[k][n])
    const void* bk   = d_in[4];
    const void* Wv   = d_in[5];
    const void* bv   = d_in[6];
    const void* Wq   = d_in[7];   // [2560,512]
    const void* bq   = d_in[8];
    const void* Wmel = d_in[9];   // [512,1280]
    const void* bmel = d_in[10];
    float* out = (float*)d_out;   // [16,64,20,2048] FP32

    char* ws = (char*)d_ws;
    size_t off = 0;
    auto alloc = [&](size_t bytes) -> ushort* {
        char* p = ws + off;
        off += (bytes + 255) & ~(size_t)255;
        return (ushort*)p;
    };
    int*    flag = (int*)alloc(256);
    ushort* vbuf = alloc((size_t)16 * 1024 * 512 * 2);   // v   [B][S][D]  bf16
    ushort* q    = alloc((size_t)16 * 2048 * 512 * 2);   // q   [B][T][D]; reused as val

    // fp32 d_out = 168MB; first 84MB hosts bf16 scratch: sc + kT.
    ushort* sc = (ushort*)d_out;                          // [B][T][S] bf16
    ushort* kT = (ushort*)d_out + (size_t)16 * 2048 * 1024; // [B][D][S] bf16

    sniff_dtype<<<1, 64, 0, stream>>>((const uint32_t*)ph, flag);

    const dim3 blk(16, 16);
    // kT[b][d][s] = ph[b][s] @ Wk[:,d] + bk[d]   (transposed bf16 store)
    ngemm<1, 1, 1, 1><<<dim3(32, 64, 16), blk, 0, stream>>>(
        ph, Wk, kT, bk, 1024, 512, 512,
        512, 1, 1024L * 512,  512, 1, 0,  1024, 512L * 1024, 1.f, flag);
    // v[b][s][d] = ph[b] @ Wv + bv
    ngemm<1, 1, 0, 1><<<dim3(32, 64, 16), blk, 0, stream>>>(
        ph, Wv, vbuf, bv, 1024, 512, 512,
        512, 1, 1024L * 512,  512, 1, 0,  512, 1024L * 512, 1.f, flag);
    // q[b][t][d] = g[b][:, t] . Wq[:, d] + bq[d]   (A = g^T via strides)
    ngemm<1, 1, 0, 1><<<dim3(32, 128, 16), blk, 0, stream>>>(
        g, Wq, q, bq, 2048, 512, 2560,
        1, 2048, 2560L * 2048,  512, 1, 0,  512, 2048L * 512, 1.f, flag);
    // sc[b][t][s] = q[b][t] . kT[b][:, s] / sqrt(512)
    ngemm<0, 0, 0, 0><<<dim3(64, 128, 16), blk, 0, stream>>>(
        q, kT, sc, nullptr, 2048, 1024, 512,
        512, 1, 2048L * 512,  1024, 1, 512L * 1024,  1024, 2048L * 1024,
        0.044194173824159216f, flag);
    // masked softmax in place
    softmax_mask<<<dim3(2048, 16), 256, 0, stream>>>(sc, len);
    // val[b][t][d] = P[b][t] . v[b][:, d]   -> reuse q buffer
    ngemm<0, 0, 0, 0><<<dim3(32, 128, 16), blk, 0, stream>>>(
        sc, vbuf, q, nullptr, 2048, 512, 1024,
        1024, 1, 2048L * 1024,  512, 1, 1024L * 512,  512, 2048L * 512, 1.f, flag);
    // out[b][j][f][t] = val[b][t] . Wmel[:, f*64+j] + bmel  (FP32 final store)
    ngemm<0, 1, 2, 1><<<dim3(80, 128, 16), blk, 0, stream>>>(
        q, Wmel, out, bmel, 2048, 1280, 512,
        512, 1, 2048L * 512,  1280, 1, 0,  0, 64L * 20 * 2048, 1.f, flag);
}